// Round 1
// baseline (793.589 us; speedup 1.0000x reference)
//
#include <hip/hip_runtime.h>
#include <hip/hip_bf16.h>
#include <stdint.h>

// MoE: B=2,S=2048 -> T=4096 tokens, H=1024, E=8 (top-2), I=2048, IS=4096. fp32 in/out.
// Strategy: cast everything to bf16 (weights transposed to [N][K]) once per launch,
// then m97-style 128x128 MFMA GEMMs with global_load_lds staging.
// Expert path = grouped GEMM over gathered rows (8192 rows total), scatter-add out.

typedef __attribute__((ext_vector_type(8))) short bf16x8;   // MFMA A/B frag (8 bf16)
typedef __attribute__((ext_vector_type(4))) float f32x4;    // MFMA C/D frag
typedef unsigned short u16;

static constexpr int Tt  = 4096;   // tokens
static constexpr int Hd  = 1024;   // hidden
static constexpr int NE  = 8;      // experts
static constexpr int Id  = 2048;   // expert intermediate
static constexpr int ISd = 4096;   // shared intermediate
static constexpr int NR  = Tt * 2; // gathered rows (top-2)
static constexpr int BM = 128, BN = 128, BK = 32;
static constexpr int MAXT = NR / BM + NE; // 72 worst-case M-tile slots

__device__ __forceinline__ u16 f2bf(float f) {  // RNE float->bf16
  union { float f; uint32_t u; } v; v.f = f;
  uint32_t u = v.u;
  u += 0x7fffu + ((u >> 16) & 1u);
  return (u16)(u >> 16);
}

// async global->LDS, 16B per lane; lds dest must be wave-uniform base (+lane*16 implicit)
__device__ __forceinline__ void ld16(void* l, const void* g) {
  __builtin_amdgcn_global_load_lds((const __attribute__((address_space(1))) void*)g,
                                   (__attribute__((address_space(3))) void*)l, 16, 0, 0);
}

// ---------------- preprocessing ----------------

__global__ void k_cvt(const float* __restrict__ s, u16* __restrict__ d, int n) {
  int i = (blockIdx.x * 256 + threadIdx.x) * 8;
  if (i >= n) return;
  float4 a = *(const float4*)(s + i);
  float4 b = *(const float4*)(s + i + 4);
  union { u16 h[8]; uint4 v; } o;
  o.h[0] = f2bf(a.x); o.h[1] = f2bf(a.y); o.h[2] = f2bf(a.z); o.h[3] = f2bf(a.w);
  o.h[4] = f2bf(b.x); o.h[5] = f2bf(b.y); o.h[6] = f2bf(b.z); o.h[7] = f2bf(b.w);
  *(uint4*)(d + i) = o.v;
}

// transpose-convert: src fp32 [b][K][N] row-major -> dst bf16 [b][N][K]
__global__ void k_tcvt(const float* __restrict__ src, u16* __restrict__ dst, int K, int N) {
  __shared__ float s[32][33];
  int b = blockIdx.z;
  const float* S = src + (size_t)b * K * N;
  u16* D = dst + (size_t)b * K * N;
  int n0 = blockIdx.x * 32, k0 = blockIdx.y * 32;
  int tx = threadIdx.x, ty = threadIdx.y; // 32 x 8
  #pragma unroll
  for (int i = 0; i < 32; i += 8)
    s[ty + i][tx] = S[(size_t)(k0 + ty + i) * N + n0 + tx];
  __syncthreads();
  #pragma unroll
  for (int i = 0; i < 32; i += 8)
    D[(size_t)(n0 + ty + i) * K + k0 + tx] = f2bf(s[tx][ty + i]);
}

// ---------------- router ----------------

__global__ void k_router(const float* __restrict__ x, const float* __restrict__ rwm,
                         int* __restrict__ sel, float* __restrict__ wts,
                         int* __restrict__ counts) {
  int t = blockIdx.x, tid = threadIdx.x;
  float p[NE];
  #pragma unroll
  for (int e = 0; e < NE; e++) p[e] = 0.f;
  const float* xt = x + (size_t)t * Hd;
  for (int j = tid; j < Hd; j += 256) {
    float v = xt[j];
    #pragma unroll
    for (int e = 0; e < NE; e++) p[e] += v * rwm[e * Hd + j];
  }
  #pragma unroll
  for (int e = 0; e < NE; e++)
    for (int o = 32; o; o >>= 1) p[e] += __shfl_down(p[e], o, 64);
  __shared__ float part[4][NE];
  int wv = tid >> 6;
  if ((tid & 63) == 0) {
    #pragma unroll
    for (int e = 0; e < NE; e++) part[wv][e] = p[e];
  }
  __syncthreads();
  if (tid == 0) {
    float l[NE];
    #pragma unroll
    for (int e = 0; e < NE; e++) l[e] = part[0][e] + part[1][e] + part[2][e] + part[3][e];
    int e0 = 0;
    for (int e = 1; e < NE; e++) if (l[e] > l[e0]) e0 = e;      // first-occurrence argmax
    int e1 = -1;
    for (int e = 0; e < NE; e++) { if (e == e0) continue; if (e1 < 0 || l[e] > l[e1]) e1 = e; }
    float w0 = 1.f / (1.f + expf(l[e1] - l[e0]));               // softmax over top-2
    sel[t * 2] = e0; sel[t * 2 + 1] = e1;
    wts[t * 2] = w0; wts[t * 2 + 1] = 1.f - w0;
    atomicAdd(&counts[e0], 1); atomicAdd(&counts[e1], 1);
  }
}

__global__ void k_offs(const int* __restrict__ counts, int* __restrict__ offs,
                       float* __restrict__ zl) {
  int a = 0;
  for (int e = 0; e < NE; e++) { offs[e] = a; a += counts[e]; }
  *zl = 0.f; // router_z_loss output
}

__global__ void k_assign(const int* __restrict__ sel, const float* __restrict__ wts,
                         const int* __restrict__ offs, int* __restrict__ cur,
                         int* __restrict__ rowtok, float* __restrict__ roww) {
  int t = blockIdx.x * 256 + threadIdx.x;
  if (t >= Tt) return;
  #pragma unroll
  for (int k = 0; k < 2; k++) {
    int e = sel[t * 2 + k];
    int r = offs[e] + atomicAdd(&cur[e], 1);
    rowtok[r] = t; roww[r] = wts[t * 2 + k];
  }
}

// ---------------- GEMM helpers ----------------

// map M-tile slot -> (rowbase, mval, expert) from per-expert counts
__device__ __forceinline__ bool tile_map(const int* offs, const int* counts, int slot,
                                         int& rowbase, int& mval, int& e_out) {
  int acc = 0, e = -1, tl = 0;
  for (int i = 0; i < NE; i++) {
    int nt = (counts[i] + BM - 1) / BM;
    if (e < 0 && slot < acc + nt) { e = i; tl = slot - acc; }
    acc += nt;
  }
  if (e < 0) return false;
  rowbase = offs[e] + tl * BM;
  int rem = counts[e] - tl * BM;
  mval = rem < BM ? rem : BM;
  e_out = e;
  return true;
}

// GEMM1: C = A[rows,1024] x {B1,B2}[N,1024]^T, fused SwiGLU -> Ho bf16 [rows][NOUT]
template <int NOUT, bool EXPERT>
__global__ __launch_bounds__(256, 2)
void k_gemm1(const u16* __restrict__ A, const u16* __restrict__ B1g,
             const u16* __restrict__ B2g, u16* __restrict__ Ho,
             const int* __restrict__ offs, const int* __restrict__ counts,
             const int* __restrict__ rowtok) {
  constexpr int KD = Hd;
  int rowbase, mval, eb = 0;
  if constexpr (EXPERT) {
    if (!tile_map(offs, counts, blockIdx.x, rowbase, mval, eb)) return;
  } else {
    rowbase = blockIdx.x * BM; mval = BM;
  }
  const int nblk = blockIdx.y;
  __shared__ u16 As[BM * BK], Bs1[BN * BK], Bs2[BN * BK];
  const int tid = threadIdx.x, w = tid >> 6, l = tid & 63;

  const u16 *aP[2], *b1P[2], *b2P[2];
  u16 *aL[2], *b1L[2], *b2L[2];
  size_t bmat = EXPERT ? (size_t)eb * NOUT * KD : 0;
  #pragma unroll
  for (int j = 0; j < 2; j++) {
    int r = w * 32 + j * 16 + (l >> 2);
    int rr = (r < mval) ? r : 0;
    int arow;
    if constexpr (EXPERT) arow = rowtok[rowbase + rr]; else arow = rowbase + rr;
    aP[j]  = A + (size_t)arow * KD + (l & 3) * 8;
    int n = nblk * BN + w * 32 + j * 16 + (l >> 2);
    b1P[j] = B1g + bmat + (size_t)n * KD + (l & 3) * 8;
    b2P[j] = B2g + bmat + (size_t)n * KD + (l & 3) * 8;
    aL[j]  = As  + (w * 32 + j * 16) * BK;
    b1L[j] = Bs1 + (w * 32 + j * 16) * BK;
    b2L[j] = Bs2 + (w * 32 + j * 16) * BK;
  }
  const int wm = w >> 1, wn = w & 1, q = l >> 4, rl = l & 15;
  f32x4 aG[4][4] = {}, aU[4][4] = {};

  for (int k0 = 0; k0 < KD; k0 += BK) {
    __syncthreads();
    #pragma unroll
    for (int j = 0; j < 2; j++) {
      ld16(aL[j],  aP[j]  + k0);
      ld16(b1L[j], b1P[j] + k0);
      ld16(b2L[j], b2P[j] + k0);
    }
    __syncthreads();
    bf16x8 af[4], bf1[4], bf2[4];
    #pragma unroll
    for (int i = 0; i < 4; i++) {
      af[i]  = *(const bf16x8*)(As  + (wm * 64 + i * 16 + rl) * BK + q * 8);
      bf1[i] = *(const bf16x8*)(Bs1 + (wn * 64 + i * 16 + rl) * BK + q * 8);
      bf2[i] = *(const bf16x8*)(Bs2 + (wn * 64 + i * 16 + rl) * BK + q * 8);
    }
    #pragma unroll
    for (int a = 0; a < 4; a++)
      #pragma unroll
      for (int b = 0; b < 4; b++) {
        aG[a][b] = __builtin_amdgcn_mfma_f32_16x16x32_bf16(af[a], bf1[b], aG[a][b], 0, 0, 0);
        aU[a][b] = __builtin_amdgcn_mfma_f32_16x16x32_bf16(af[a], bf2[b], aU[a][b], 0, 0, 0);
      }
  }
  // epilogue: silu(gate)*up -> bf16. C/D layout: col = lane&15, row = (lane>>4)*4+reg
  #pragma unroll
  for (int a = 0; a < 4; a++) {
    #pragma unroll
    for (int r = 0; r < 4; r++) {
      int row = wm * 64 + a * 16 + q * 4 + r;
      if (row < mval) {
        size_t ro = (size_t)(rowbase + row) * NOUT;
        #pragma unroll
        for (int b = 0; b < 4; b++) {
          int c = nblk * BN + wn * 64 + b * 16 + rl;
          float g = aG[a][b][r], u = aU[a][b][r];
          Ho[ro + c] = f2bf(g / (1.f + __expf(-g)) * u);
        }
      }
    }
  }
}

// GEMM2: down-proj. EXPERT: out[tok] += roww * (h x Wd^T); else: out[row] = hs x Sd^T
template <int KD, bool EXPERT>
__global__ __launch_bounds__(256, 2)
void k_gemm2(const u16* __restrict__ A, const u16* __restrict__ Bg, float* __restrict__ out,
             const int* __restrict__ offs, const int* __restrict__ counts,
             const int* __restrict__ rowtok, const float* __restrict__ roww) {
  int rowbase, mval, eb = 0;
  if constexpr (EXPERT) {
    if (!tile_map(offs, counts, blockIdx.x, rowbase, mval, eb)) return;
  } else {
    rowbase = blockIdx.x * BM; mval = BM;
  }
  const int nblk = blockIdx.y;
  __shared__ u16 As[BM * BK], Bs[BN * BK];
  const int tid = threadIdx.x, w = tid >> 6, l = tid & 63;

  const u16 *aP[2], *bP[2];
  u16 *aL[2], *bL[2];
  size_t bmat = EXPERT ? (size_t)eb * Hd * KD : 0;
  #pragma unroll
  for (int j = 0; j < 2; j++) {
    int r = w * 32 + j * 16 + (l >> 2);
    int rr = (r < mval) ? r : 0;
    aP[j] = A + (size_t)(rowbase + rr) * KD + (l & 3) * 8;
    int n = nblk * BN + w * 32 + j * 16 + (l >> 2);
    bP[j] = Bg + bmat + (size_t)n * KD + (l & 3) * 8;
    aL[j] = As + (w * 32 + j * 16) * BK;
    bL[j] = Bs + (w * 32 + j * 16) * BK;
  }
  const int wm = w >> 1, wn = w & 1, q = l >> 4, rl = l & 15;
  f32x4 acc[4][4] = {};

  for (int k0 = 0; k0 < KD; k0 += BK) {
    __syncthreads();
    #pragma unroll
    for (int j = 0; j < 2; j++) {
      ld16(aL[j], aP[j] + k0);
      ld16(bL[j], bP[j] + k0);
    }
    __syncthreads();
    bf16x8 af[4], bf[4];
    #pragma unroll
    for (int i = 0; i < 4; i++) {
      af[i] = *(const bf16x8*)(As + (wm * 64 + i * 16 + rl) * BK + q * 8);
      bf[i] = *(const bf16x8*)(Bs + (wn * 64 + i * 16 + rl) * BK + q * 8);
    }
    #pragma unroll
    for (int a = 0; a < 4; a++)
      #pragma unroll
      for (int b = 0; b < 4; b++)
        acc[a][b] = __builtin_amdgcn_mfma_f32_16x16x32_bf16(af[a], bf[b], acc[a][b], 0, 0, 0);
  }
  #pragma unroll
  for (int a = 0; a < 4; a++) {
    #pragma unroll
    for (int r = 0; r < 4; r++) {
      int row = wm * 64 + a * 16 + q * 4 + r;
      if (row < mval) {
        int grow = rowbase + row;
        if constexpr (EXPERT) {
          int tok = rowtok[grow];
          float wt = roww[grow];
          size_t o = (size_t)tok * Hd;
          #pragma unroll
          for (int b = 0; b < 4; b++) {
            int c = nblk * BN + wn * 64 + b * 16 + rl;
            atomicAdd(&out[o + c], wt * acc[a][b][r]);
          }
        } else {
          size_t o = (size_t)grow * Hd;
          #pragma unroll
          for (int b = 0; b < 4; b++) {
            int c = nblk * BN + wn * 64 + b * 16 + rl;
            out[o + c] = acc[a][b][r];
          }
        }
      }
    }
  }
}

// ---------------- launch ----------------

extern "C" void kernel_launch(void* const* d_in, const int* in_sizes, int n_in,
                              void* d_out, int out_size, void* d_ws, size_t ws_size,
                              hipStream_t stream) {
  const float* x   = (const float*)d_in[0];
  const float* rwm = (const float*)d_in[1];
  const float* Wg  = (const float*)d_in[2];
  const float* Wu  = (const float*)d_in[3];
  const float* Wd  = (const float*)d_in[4];
  const float* Sg  = (const float*)d_in[5];
  const float* Su  = (const float*)d_in[6];
  const float* Sd  = (const float*)d_in[7];
  float* out = (float*)d_out;

  uint8_t* p = (uint8_t*)d_ws;
  auto take = [&](size_t bytes) { uint8_t* r = p; p += ((bytes + 255) & ~(size_t)255); return r; };
  u16* xb   = (u16*)take((size_t)Tt * Hd * 2);
  u16* Wgt  = (u16*)take((size_t)NE * Id * Hd * 2);   // [E][I][H]
  u16* Wut  = (u16*)take((size_t)NE * Id * Hd * 2);
  u16* Wdt  = (u16*)take((size_t)NE * Hd * Id * 2);   // [E][H][I]
  u16* Sgt  = (u16*)take((size_t)ISd * Hd * 2);       // [IS][H]
  u16* Sut  = (u16*)take((size_t)ISd * Hd * 2);
  u16* Sdt  = (u16*)take((size_t)Hd * ISd * 2);       // [H][IS]
  u16* hbuf = (u16*)take((size_t)NR * Id * 2);        // == Tt*ISd*2; reused for hs then h
  int*   sel    = (int*)take(Tt * 2 * 4);
  float* wts    = (float*)take(Tt * 2 * 4);
  int*   rowtok = (int*)take(NR * 4);
  float* roww   = (float*)take(NR * 4);
  int*   counts = (int*)take(NE * 4);
  int*   offs   = (int*)take(NE * 4);
  int*   cur    = (int*)take(NE * 4);

  hipMemsetAsync(counts, 0, NE * 4, stream);
  hipMemsetAsync(cur, 0, NE * 4, stream);

  // bf16 casts / transposes
  k_cvt<<<(Tt * Hd / 8 + 255) / 256, 256, 0, stream>>>(x, xb, Tt * Hd);
  k_tcvt<<<dim3(Id / 32, Hd / 32, NE), dim3(32, 8), 0, stream>>>(Wg, Wgt, Hd, Id);
  k_tcvt<<<dim3(Id / 32, Hd / 32, NE), dim3(32, 8), 0, stream>>>(Wu, Wut, Hd, Id);
  k_tcvt<<<dim3(Hd / 32, Id / 32, NE), dim3(32, 8), 0, stream>>>(Wd, Wdt, Id, Hd);
  k_tcvt<<<dim3(ISd / 32, Hd / 32, 1), dim3(32, 8), 0, stream>>>(Sg, Sgt, Hd, ISd);
  k_tcvt<<<dim3(ISd / 32, Hd / 32, 1), dim3(32, 8), 0, stream>>>(Su, Sut, Hd, ISd);
  k_tcvt<<<dim3(Hd / 32, ISd / 32, 1), dim3(32, 8), 0, stream>>>(Sd, Sdt, ISd, Hd);

  // routing
  k_router<<<Tt, 256, 0, stream>>>(x, rwm, sel, wts, counts);
  k_offs<<<1, 1, 0, stream>>>(counts, offs, out + (size_t)Tt * Hd);
  k_assign<<<Tt / 256, 256, 0, stream>>>(sel, wts, offs, cur, rowtok, roww);

  // shared expert: hs = silu(x Sg)*(x Su); out = hs Sd   (plain stores cover all of out)
  k_gemm1<ISd, false><<<dim3(Tt / BM, ISd / BN), 256, 0, stream>>>(xb, Sgt, Sut, hbuf,
                                                                  nullptr, nullptr, nullptr);
  k_gemm2<ISd, false><<<dim3(Tt / BM, Hd / BN), 256, 0, stream>>>(hbuf, Sdt, out,
                                                                  nullptr, nullptr, nullptr, nullptr);
  // experts: h = silu(xg Wg)*(xg Wu); out += roww * (h Wd)   (atomic adds)
  k_gemm1<Id, true><<<dim3(MAXT, Id / BN), 256, 0, stream>>>(xb, Wgt, Wut, hbuf,
                                                             offs, counts, rowtok);
  k_gemm2<Id, true><<<dim3(MAXT, Hd / BN), 256, 0, stream>>>(hbuf, Wdt, out,
                                                             offs, counts, rowtok, roww);
}

// Round 2
// 769.607 us; speedup vs baseline: 1.0312x; 1.0312x over previous
//
#include <hip/hip_runtime.h>
#include <hip/hip_bf16.h>
#include <stdint.h>

// MoE: T=4096 tokens, H=1024, E=8 (top-2), I=2048, IS=4096. fp32 in/out.
// bf16 MFMA pipeline: cast/transpose weights once per launch, m97-style GEMMs
// with global_load_lds staging, XCD-slab block swizzle, XOR LDS-bank swizzle.

typedef __attribute__((ext_vector_type(8))) short bf16x8;   // MFMA A/B frag
typedef __attribute__((ext_vector_type(4))) float f32x4;    // MFMA C/D frag
typedef unsigned short u16;

static constexpr int Tt  = 4096;
static constexpr int Hd  = 1024;
static constexpr int NE  = 8;
static constexpr int Id  = 2048;
static constexpr int ISd = 4096;
static constexpr int NR  = Tt * 2;
static constexpr int BM = 128, BN = 128, BN1 = 64, BK = 32;
static constexpr int MAXT = NR / BM + NE; // 72 worst-case expert M-tile slots

__device__ __forceinline__ u16 f2bf(float f) {  // RNE float->bf16
  union { float f; uint32_t u; } v; v.f = f;
  uint32_t u = v.u;
  u += 0x7fffu + ((u >> 16) & 1u);
  return (u16)(u >> 16);
}

__device__ __forceinline__ void ld16(void* l, const void* g) {
  __builtin_amdgcn_global_load_lds((const __attribute__((address_space(1))) void*)g,
                                   (__attribute__((address_space(3))) void*)l, 16, 0, 0);
}

// LDS bank swizzle: row r's k-chunk q lives at slot q ^ ((r>>1)&3).
// Staging lane l (row l>>2 within its 16-row chunk) therefore fetches global
// k-chunk (l&3) ^ ((tile_row>>1)&3). Frag reads mirror it -> 2-way max (free).
__device__ __forceinline__ const u16* fragp(const u16* base, int row, int q) {
  return base + row * BK + ((q ^ ((row >> 1) & 3)) * 8);
}

// ---------------- preprocessing ----------------

__global__ void k_cvt(const float* __restrict__ s, u16* __restrict__ d, int n) {
  int i = (blockIdx.x * 256 + threadIdx.x) * 8;
  if (i >= n) return;
  float4 a = *(const float4*)(s + i);
  float4 b = *(const float4*)(s + i + 4);
  union { u16 h[8]; uint4 v; } o;
  o.h[0] = f2bf(a.x); o.h[1] = f2bf(a.y); o.h[2] = f2bf(a.z); o.h[3] = f2bf(a.w);
  o.h[4] = f2bf(b.x); o.h[5] = f2bf(b.y); o.h[6] = f2bf(b.z); o.h[7] = f2bf(b.w);
  *(uint4*)(d + i) = o.v;
}

// transpose-convert: src fp32 [b][K][N] -> dst bf16 [b][N][K]; ushort4 stores
__global__ void k_tcvt(const float* __restrict__ src, u16* __restrict__ dst, int K, int N) {
  __shared__ float s[32][33];
  int b = blockIdx.z;
  const float* S = src + (size_t)b * K * N;
  u16* D = dst + (size_t)b * K * N;
  int n0 = blockIdx.x * 32, k0 = blockIdx.y * 32;
  int tid = threadIdx.x;
  int tx = tid & 31, ty = tid >> 5;
  #pragma unroll
  for (int i = 0; i < 32; i += 8)
    s[ty + i][tx] = S[(size_t)(k0 + ty + i) * N + n0 + tx];
  __syncthreads();
  int n = tid >> 3, kq = (tid & 7) * 4;
  ushort4 o;
  o.x = f2bf(s[kq][n]); o.y = f2bf(s[kq + 1][n]);
  o.z = f2bf(s[kq + 2][n]); o.w = f2bf(s[kq + 3][n]);
  *(ushort4*)&D[(size_t)(n0 + n) * K + k0 + kq] = o;
}

// ---------------- router ----------------

__global__ void k_router(const float* __restrict__ x, const float* __restrict__ rwm,
                         int* __restrict__ sel, float* __restrict__ wts,
                         int* __restrict__ counts) {
  int t = blockIdx.x, tid = threadIdx.x;
  float p[NE];
  #pragma unroll
  for (int e = 0; e < NE; e++) p[e] = 0.f;
  const float* xt = x + (size_t)t * Hd;
  for (int j = tid; j < Hd; j += 256) {
    float v = xt[j];
    #pragma unroll
    for (int e = 0; e < NE; e++) p[e] += v * rwm[e * Hd + j];
  }
  #pragma unroll
  for (int e = 0; e < NE; e++)
    for (int o = 32; o; o >>= 1) p[e] += __shfl_down(p[e], o, 64);
  __shared__ float part[4][NE];
  int wv = tid >> 6;
  if ((tid & 63) == 0) {
    #pragma unroll
    for (int e = 0; e < NE; e++) part[wv][e] = p[e];
  }
  __syncthreads();
  if (tid == 0) {
    float l[NE];
    #pragma unroll
    for (int e = 0; e < NE; e++) l[e] = part[0][e] + part[1][e] + part[2][e] + part[3][e];
    int e0 = 0;
    for (int e = 1; e < NE; e++) if (l[e] > l[e0]) e0 = e;
    int e1 = -1;
    for (int e = 0; e < NE; e++) { if (e == e0) continue; if (e1 < 0 || l[e] > l[e1]) e1 = e; }
    float w0 = 1.f / (1.f + expf(l[e1] - l[e0]));
    sel[t * 2] = e0; sel[t * 2 + 1] = e1;
    wts[t * 2] = w0; wts[t * 2 + 1] = 1.f - w0;
    atomicAdd(&counts[e0], 1); atomicAdd(&counts[e1], 1);
  }
}

__global__ void k_offs(const int* __restrict__ counts, int* __restrict__ offs) {
  int a = 0;
  for (int e = 0; e < NE; e++) { offs[e] = a; a += counts[e]; }
}

__global__ void k_assign(const int* __restrict__ sel, const float* __restrict__ wts,
                         const int* __restrict__ offs, int* __restrict__ cur,
                         int* __restrict__ rowtok, float* __restrict__ roww) {
  int t = blockIdx.x * 256 + threadIdx.x;
  if (t >= Tt) return;
  #pragma unroll
  for (int k = 0; k < 2; k++) {
    int e = sel[t * 2 + k];
    int r = offs[e] + atomicAdd(&cur[e], 1);
    rowtok[r] = t; roww[r] = wts[t * 2 + k];
  }
}

// ---------------- GEMM helpers ----------------

__device__ __forceinline__ bool tile_map(const int* offs, const int* counts, int slot,
                                         int& rowbase, int& mval, int& e_out) {
  int acc = 0, e = -1, tl = 0;
  for (int i = 0; i < NE; i++) {
    int nt = (counts[i] + BM - 1) / BM;
    if (e < 0 && slot < acc + nt) { e = i; tl = slot - acc; }
    acc += nt;
  }
  if (e < 0) return false;
  rowbase = offs[e] + tl * BM;
  int rem = counts[e] - tl * BM;
  mval = rem < BM ? rem : BM;
  e_out = e;
  return true;
}

// GEMM1: 128x64 tile. C = A[rows,H] x {B1,B2}[N,H]^T, fused SwiGLU -> Ho bf16.
// Flat grid with XCD N-slab swizzle: xcd = bid&7 owns N-slab, m fastest within.
template <int NOUT, bool EXPERT>
__global__ __launch_bounds__(256, 3)
void k_gemm1(const u16* __restrict__ A, const u16* __restrict__ B1g,
             const u16* __restrict__ B2g, u16* __restrict__ Ho,
             const int* __restrict__ offs, const int* __restrict__ counts,
             const int* __restrict__ rowtok) {
  constexpr int KD = Hd;
  constexpr int NT = NOUT / BN1;
  constexpr int slabN = NT / 8;
  int bid = blockIdx.x;
  int xcd = bid & 7, idx = bid >> 3;
  int n = xcd * slabN + idx % slabN;
  int mt = idx / slabN;
  int rowbase, mval, eb = 0;
  if constexpr (EXPERT) {
    if (!tile_map(offs, counts, mt, rowbase, mval, eb)) return;
  } else {
    rowbase = mt * BM; mval = BM;
  }
  __shared__ u16 As[BM * BK], Bs1[BN1 * BK], Bs2[BN1 * BK];
  const int tid = threadIdx.x, w = tid >> 6, l = tid & 63;

  const u16 *aP[2], *b1P, *b2P;
  u16 *aL[2], *b1L, *b2L;
  size_t bmat = EXPERT ? (size_t)eb * NOUT * KD : 0;
  #pragma unroll
  for (int j = 0; j < 2; j++) {
    int r = w * 32 + j * 16 + (l >> 2);
    int rr = (r < mval) ? r : 0;
    int arow;
    if constexpr (EXPERT) arow = rowtok[rowbase + rr]; else arow = rowbase + rr;
    int cg = (l & 3) ^ ((r >> 1) & 3);
    aP[j] = A + (size_t)arow * KD + cg * 8;
    aL[j] = As + (w * 32 + j * 16) * BK;
  }
  {
    int r = w * 16 + (l >> 2);
    int nn = n * BN1 + r;
    int cg = (l & 3) ^ ((r >> 1) & 3);
    b1P = B1g + bmat + (size_t)nn * KD + cg * 8;
    b2P = B2g + bmat + (size_t)nn * KD + cg * 8;
    b1L = Bs1 + (w * 16) * BK;
    b2L = Bs2 + (w * 16) * BK;
  }
  const int wm = w >> 1, wn = w & 1, q = l >> 4, rl = l & 15;
  f32x4 aG[4][2] = {}, aU[4][2] = {};

  for (int k0 = 0; k0 < KD; k0 += BK) {
    __syncthreads();
    ld16(aL[0], aP[0] + k0);
    ld16(aL[1], aP[1] + k0);
    ld16(b1L, b1P + k0);
    ld16(b2L, b2P + k0);
    __syncthreads();
    bf16x8 af[4], bf1[2], bf2[2];
    #pragma unroll
    for (int i = 0; i < 4; i++) {
      int row = wm * 64 + i * 16 + rl;
      af[i] = *(const bf16x8*)fragp(As, row, q);
    }
    #pragma unroll
    for (int i = 0; i < 2; i++) {
      int row = wn * 32 + i * 16 + rl;
      bf1[i] = *(const bf16x8*)fragp(Bs1, row, q);
      bf2[i] = *(const bf16x8*)fragp(Bs2, row, q);
    }
    #pragma unroll
    for (int a = 0; a < 4; a++)
      #pragma unroll
      for (int b = 0; b < 2; b++) {
        aG[a][b] = __builtin_amdgcn_mfma_f32_16x16x32_bf16(af[a], bf1[b], aG[a][b], 0, 0, 0);
        aU[a][b] = __builtin_amdgcn_mfma_f32_16x16x32_bf16(af[a], bf2[b], aU[a][b], 0, 0, 0);
      }
  }
  #pragma unroll
  for (int a = 0; a < 4; a++) {
    #pragma unroll
    for (int r = 0; r < 4; r++) {
      int row = wm * 64 + a * 16 + q * 4 + r;
      if (row < mval) {
        size_t ro = (size_t)(rowbase + row) * NOUT;
        #pragma unroll
        for (int b = 0; b < 2; b++) {
          int c = n * BN1 + wn * 32 + b * 16 + rl;
          float g = aG[a][b][r], u = aU[a][b][r];
          Ho[ro + c] = f2bf(g / (1.f + __expf(-g)) * u);
        }
      }
    }
  }
}

// GEMM2: 128x128 tile, split-K, atomic-add epilogue (out pre-zeroed).
template <int KD, int KSPLIT, bool EXPERT>
__global__ __launch_bounds__(256, 3)
void k_gemm2(const u16* __restrict__ A, const u16* __restrict__ Bg, float* __restrict__ out,
             const int* __restrict__ offs, const int* __restrict__ counts,
             const int* __restrict__ rowtok, const float* __restrict__ roww) {
  constexpr int NT = Hd / BN;                 // 8
  constexpr int MT = EXPERT ? MAXT : (Tt / BM);
  constexpr int KC = KD / KSPLIT;
  int bid = blockIdx.x;
  int n = bid % NT;
  int rest = bid / NT;
  int mt = rest % MT, kz = rest / MT;
  int rowbase, mval, eb = 0;
  if constexpr (EXPERT) {
    if (!tile_map(offs, counts, mt, rowbase, mval, eb)) return;
  } else {
    rowbase = mt * BM; mval = BM;
  }
  __shared__ u16 As[BM * BK], Bs[BN * BK];
  const int tid = threadIdx.x, w = tid >> 6, l = tid & 63;

  const u16 *aP[2], *bP[2];
  u16 *aL[2], *bL[2];
  size_t bmat = EXPERT ? (size_t)eb * Hd * KD : 0;
  #pragma unroll
  for (int j = 0; j < 2; j++) {
    int r = w * 32 + j * 16 + (l >> 2);
    int rr = (r < mval) ? r : 0;
    int cg = (l & 3) ^ ((r >> 1) & 3);
    aP[j] = A + (size_t)(rowbase + rr) * KD + cg * 8;
    int nn = n * BN + r;
    bP[j] = Bg + bmat + (size_t)nn * KD + cg * 8;
    aL[j] = As + (w * 32 + j * 16) * BK;
    bL[j] = Bs + (w * 32 + j * 16) * BK;
  }
  const int wm = w >> 1, wn = w & 1, q = l >> 4, rl = l & 15;
  f32x4 acc[4][4] = {};

  const int kend = kz * KC + KC;
  for (int k0 = kz * KC; k0 < kend; k0 += BK) {
    __syncthreads();
    #pragma unroll
    for (int j = 0; j < 2; j++) {
      ld16(aL[j], aP[j] + k0);
      ld16(bL[j], bP[j] + k0);
    }
    __syncthreads();
    bf16x8 af[4], bf[4];
    #pragma unroll
    for (int i = 0; i < 4; i++) {
      int rowa = wm * 64 + i * 16 + rl;
      int rowb = wn * 64 + i * 16 + rl;
      af[i] = *(const bf16x8*)fragp(As, rowa, q);
      bf[i] = *(const bf16x8*)fragp(Bs, rowb, q);
    }
    #pragma unroll
    for (int a = 0; a < 4; a++)
      #pragma unroll
      for (int b = 0; b < 4; b++)
        acc[a][b] = __builtin_amdgcn_mfma_f32_16x16x32_bf16(af[a], bf[b], acc[a][b], 0, 0, 0);
  }
  #pragma unroll
  for (int a = 0; a < 4; a++) {
    #pragma unroll
    for (int r = 0; r < 4; r++) {
      int row = wm * 64 + a * 16 + q * 4 + r;
      if (row < mval) {
        int grow = rowbase + row;
        float wt = 1.f;
        size_t o;
        if constexpr (EXPERT) {
          o = (size_t)rowtok[grow] * Hd;
          wt = roww[grow];
        } else {
          o = (size_t)grow * Hd;
        }
        #pragma unroll
        for (int b = 0; b < 4; b++) {
          int c = n * BN + wn * 64 + b * 16 + rl;
          atomicAdd(&out[o + c], wt * acc[a][b][r]);
        }
      }
    }
  }
}

// ---------------- launch ----------------

extern "C" void kernel_launch(void* const* d_in, const int* in_sizes, int n_in,
                              void* d_out, int out_size, void* d_ws, size_t ws_size,
                              hipStream_t stream) {
  const float* x   = (const float*)d_in[0];
  const float* rwm = (const float*)d_in[1];
  const float* Wg  = (const float*)d_in[2];
  const float* Wu  = (const float*)d_in[3];
  const float* Wd  = (const float*)d_in[4];
  const float* Sg  = (const float*)d_in[5];
  const float* Su  = (const float*)d_in[6];
  const float* Sd  = (const float*)d_in[7];
  float* out = (float*)d_out;

  uint8_t* p = (uint8_t*)d_ws;
  auto take = [&](size_t bytes) { uint8_t* r = p; p += ((bytes + 255) & ~(size_t)255); return r; };
  u16* xb   = (u16*)take((size_t)Tt * Hd * 2);
  u16* Wgt  = (u16*)take((size_t)NE * Id * Hd * 2);   // [E][I][H]
  u16* Wut  = (u16*)take((size_t)NE * Id * Hd * 2);
  u16* Wdt  = (u16*)take((size_t)NE * Hd * Id * 2);   // [E][H][I]
  u16* Sgt  = (u16*)take((size_t)ISd * Hd * 2);       // [IS][H]
  u16* Sut  = (u16*)take((size_t)ISd * Hd * 2);
  u16* Sdt  = (u16*)take((size_t)Hd * ISd * 2);       // [H][IS]
  u16* hbuf = (u16*)take((size_t)NR * Id * 2);        // reused: hs then h
  int*   sel    = (int*)take(Tt * 2 * 4);
  float* wts    = (float*)take(Tt * 2 * 4);
  int*   rowtok = (int*)take(NR * 4);
  float* roww   = (float*)take(NR * 4);
  int*   counts = (int*)take(NE * 4);
  int*   offs   = (int*)take(NE * 4);
  int*   cur    = (int*)take(NE * 4);

  hipMemsetAsync(counts, 0, NE * 4, stream);
  hipMemsetAsync(cur, 0, NE * 4, stream);
  hipMemsetAsync(out, 0, (size_t)out_size * 4, stream);  // gemm2s accumulate atomically

  k_cvt<<<(Tt * Hd / 8 + 255) / 256, 256, 0, stream>>>(x, xb, Tt * Hd);
  k_tcvt<<<dim3(Id / 32, Hd / 32, NE), 256, 0, stream>>>(Wg, Wgt, Hd, Id);
  k_tcvt<<<dim3(Id / 32, Hd / 32, NE), 256, 0, stream>>>(Wu, Wut, Hd, Id);
  k_tcvt<<<dim3(Hd / 32, Id / 32, NE), 256, 0, stream>>>(Wd, Wdt, Id, Hd);
  k_tcvt<<<dim3(ISd / 32, Hd / 32, 1), 256, 0, stream>>>(Sg, Sgt, Hd, ISd);
  k_tcvt<<<dim3(ISd / 32, Hd / 32, 1), 256, 0, stream>>>(Su, Sut, Hd, ISd);
  k_tcvt<<<dim3(Hd / 32, ISd / 32, 1), 256, 0, stream>>>(Sd, Sdt, ISd, Hd);

  k_router<<<Tt, 256, 0, stream>>>(x, rwm, sel, wts, counts);
  k_offs<<<1, 1, 0, stream>>>(counts, offs);
  k_assign<<<Tt / 256, 256, 0, stream>>>(sel, wts, offs, cur, rowtok, roww);

  // shared expert
  k_gemm1<ISd, false><<<(Tt / BM) * (ISd / BN1), 256, 0, stream>>>(
      xb, Sgt, Sut, hbuf, nullptr, nullptr, nullptr);
  k_gemm2<ISd, 2, false><<<(Hd / BN) * (Tt / BM) * 2, 256, 0, stream>>>(
      hbuf, Sdt, out, nullptr, nullptr, nullptr, nullptr);
  // routed experts
  k_gemm1<Id, true><<<MAXT * (Id / BN1), 256, 0, stream>>>(
      xb, Wgt, Wut, hbuf, offs, counts, rowtok);
  k_gemm2<Id, 2, true><<<(Hd / BN) * MAXT * 2, 256, 0, stream>>>(
      hbuf, Wdt, out, offs, counts, rowtok, roww);
}

// Round 3
// 713.977 us; speedup vs baseline: 1.1115x; 1.0779x over previous
//
#include <hip/hip_runtime.h>
#include <hip/hip_bf16.h>
#include <stdint.h>

// MoE: T=4096 tokens, H=1024, E=8 (top-2), I=2048, IS=4096. fp32 in/out.
// bf16 MFMA pipeline: cast/transpose weights once per launch, BK=64 GEMMs with
// global_load_lds staging, XCD n-slab swizzle, XOR LDS-bank swizzle (row&7).

typedef __attribute__((ext_vector_type(8))) short bf16x8;   // MFMA A/B frag
typedef __attribute__((ext_vector_type(4))) float f32x4;    // MFMA C/D frag
typedef unsigned short u16;

static constexpr int Tt  = 4096;
static constexpr int Hd  = 1024;
static constexpr int NE  = 8;
static constexpr int Id  = 2048;
static constexpr int ISd = 4096;
static constexpr int NR  = Tt * 2;
static constexpr int BM = 128, BN = 128, BN1 = 64, BK = 64;
static constexpr int MAXT = NR / BM + NE; // 72 worst-case expert M-tile slots

__device__ __forceinline__ u16 f2bf(float f) {  // RNE float->bf16
  union { float f; uint32_t u; } v; v.f = f;
  uint32_t u = v.u;
  u += 0x7fffu + ((u >> 16) & 1u);
  return (u16)(u >> 16);
}

__device__ __forceinline__ void ld16(void* l, const void* g) {
  __builtin_amdgcn_global_load_lds((const __attribute__((address_space(1))) void*)g,
                                   (__attribute__((address_space(3))) void*)l, 16, 0, 0);
}

// ---------------- preprocessing ----------------

__global__ void k_cvt(const float* __restrict__ s, u16* __restrict__ d, int n) {
  int i = (blockIdx.x * 256 + threadIdx.x) * 8;
  if (i >= n) return;
  float4 a = *(const float4*)(s + i);
  float4 b = *(const float4*)(s + i + 4);
  union { u16 h[8]; uint4 v; } o;
  o.h[0] = f2bf(a.x); o.h[1] = f2bf(a.y); o.h[2] = f2bf(a.z); o.h[3] = f2bf(a.w);
  o.h[4] = f2bf(b.x); o.h[5] = f2bf(b.y); o.h[6] = f2bf(b.z); o.h[7] = f2bf(b.w);
  *(uint4*)(d + i) = o.v;
}

// transpose-convert: fp32 [z][K][N] -> bf16 [z][N][K]. 64x64 tiles.
// reads float4 (16B/lane), writes ushort8 (16B/lane, 128B per n-row).
// two tensor pairs per dispatch: z < nzA -> (srcA,dstA) else (srcB,dstB).
__global__ __launch_bounds__(256)
void k_tcvt(const float* __restrict__ srcA, u16* __restrict__ dstA,
            const float* __restrict__ srcB, u16* __restrict__ dstB,
            int K, int N, int nzA) {
  __shared__ float s[64][65];
  int z = blockIdx.z;
  const float* S; u16* D;
  if (z < nzA) { S = srcA + (size_t)z * K * N; D = dstA + (size_t)z * K * N; }
  else { z -= nzA; S = srcB + (size_t)z * K * N; D = dstB + (size_t)z * K * N; }
  int n0 = blockIdx.x * 64, k0 = blockIdx.y * 64;
  int tid = threadIdx.x;
  int rr = tid >> 4, cc = (tid & 15) * 4;
  #pragma unroll
  for (int i = 0; i < 4; i++) {
    float4 v = *(const float4*)&S[(size_t)(k0 + i * 16 + rr) * N + n0 + cc];
    s[i * 16 + rr][cc] = v.x; s[i * 16 + rr][cc + 1] = v.y;
    s[i * 16 + rr][cc + 2] = v.z; s[i * 16 + rr][cc + 3] = v.w;
  }
  __syncthreads();
  int nn = tid >> 3, kc = (tid & 7) * 8;
  #pragma unroll
  for (int i = 0; i < 2; i++) {
    int n = i * 32 + nn;
    union { u16 h[8]; uint4 v; } o;
    #pragma unroll
    for (int t = 0; t < 8; t++) o.h[t] = f2bf(s[kc + t][n]);
    *(uint4*)&D[(size_t)(n0 + n) * K + k0 + kc] = o.v;
  }
}

// ---------------- router ----------------

__global__ void k_router(const float* __restrict__ x, const float* __restrict__ rwm,
                         int* __restrict__ sel, float* __restrict__ wts,
                         int* __restrict__ counts) {
  int t = blockIdx.x, tid = threadIdx.x;
  float p[NE];
  #pragma unroll
  for (int e = 0; e < NE; e++) p[e] = 0.f;
  const float* xt = x + (size_t)t * Hd;
  for (int j = tid; j < Hd; j += 256) {
    float v = xt[j];
    #pragma unroll
    for (int e = 0; e < NE; e++) p[e] += v * rwm[e * Hd + j];
  }
  #pragma unroll
  for (int e = 0; e < NE; e++)
    for (int o = 32; o; o >>= 1) p[e] += __shfl_down(p[e], o, 64);
  __shared__ float part[4][NE];
  int wv = tid >> 6;
  if ((tid & 63) == 0) {
    #pragma unroll
    for (int e = 0; e < NE; e++) part[wv][e] = p[e];
  }
  __syncthreads();
  if (tid == 0) {
    float l[NE];
    #pragma unroll
    for (int e = 0; e < NE; e++) l[e] = part[0][e] + part[1][e] + part[2][e] + part[3][e];
    int e0 = 0;
    for (int e = 1; e < NE; e++) if (l[e] > l[e0]) e0 = e;
    int e1 = -1;
    for (int e = 0; e < NE; e++) { if (e == e0) continue; if (e1 < 0 || l[e] > l[e1]) e1 = e; }
    float w0 = 1.f / (1.f + expf(l[e1] - l[e0]));
    sel[t * 2] = e0; sel[t * 2 + 1] = e1;
    wts[t * 2] = w0; wts[t * 2 + 1] = 1.f - w0;
    atomicAdd(&counts[e0], 1); atomicAdd(&counts[e1], 1);
  }
}

__global__ void k_offs(const int* __restrict__ counts, int* __restrict__ offs) {
  int a = 0;
  for (int e = 0; e < NE; e++) { offs[e] = a; a += counts[e]; }
}

__global__ void k_assign(const int* __restrict__ sel, const float* __restrict__ wts,
                         const int* __restrict__ offs, int* __restrict__ cur,
                         int* __restrict__ rowtok, float* __restrict__ roww) {
  int t = blockIdx.x * 256 + threadIdx.x;
  if (t >= Tt) return;
  #pragma unroll
  for (int k = 0; k < 2; k++) {
    int e = sel[t * 2 + k];
    int r = offs[e] + atomicAdd(&cur[e], 1);
    rowtok[r] = t; roww[r] = wts[t * 2 + k];
  }
}

// ---------------- GEMM helpers ----------------

__device__ __forceinline__ bool tile_map(const int* offs, const int* counts, int slot,
                                         int& rowbase, int& mval, int& e_out) {
  int acc = 0, e = -1, tl = 0;
  for (int i = 0; i < NE; i++) {
    int nt = (counts[i] + BM - 1) / BM;
    if (e < 0 && slot < acc + nt) { e = i; tl = slot - acc; }
    acc += nt;
  }
  if (e < 0) return false;
  rowbase = offs[e] + tl * BM;
  int rem = counts[e] - tl * BM;
  mval = rem < BM ? rem : BM;
  e_out = e;
  return true;
}

// LDS layout (BK=64): row = 128 B = 8 chunks of 16 B. Logical chunk c of row r
// stored at slot c ^ (r & 7) -> frag reads across 16 rows spread all 8 bank
// groups 2-way (free). Staging lane l in an 8-row unit: row = l>>3, slot = l&7,
// so it fetches logical chunk (l&7) ^ (l>>3).

// GEMM1: 128x64 tile, dual B (gate+up), fused SwiGLU -> Ho bf16 [rows][NOUT].
template <int NOUT, bool EXPERT>
__global__ __launch_bounds__(256, 3)
void k_gemm1(const u16* __restrict__ A, const u16* __restrict__ B1g,
             const u16* __restrict__ B2g, u16* __restrict__ Ho,
             const int* __restrict__ offs, const int* __restrict__ counts,
             const int* __restrict__ rowtok) {
  constexpr int KD = Hd;
  constexpr int NT = NOUT / BN1;
  constexpr int slabN = NT / 8;
  int bid = blockIdx.x;
  int xcd = bid & 7, idx = bid >> 3;
  int n = xcd * slabN + idx % slabN;
  int mt = idx / slabN;
  int rowbase, mval, eb = 0;
  if constexpr (EXPERT) {
    if (!tile_map(offs, counts, mt, rowbase, mval, eb)) return;
  } else {
    rowbase = mt * BM; mval = BM;
  }
  __shared__ u16 As[BM * BK], Bs1[BN1 * BK], Bs2[BN1 * BK];
  const int tid = threadIdx.x, w = tid >> 6, l = tid & 63;
  const int lr = l >> 3;            // row within 8-row stage unit
  const int cg = (l & 7) ^ lr;      // logical chunk this lane fetches
  size_t bmat = EXPERT ? (size_t)eb * NOUT * KD : 0;

  const u16* gp[8];
  u16* lp[8];
  if (w < 2) {                      // A rows w*64 .. w*64+63
    #pragma unroll
    for (int j = 0; j < 8; j++) {
      int r = w * 64 + j * 8 + lr;
      int rr = (r < mval) ? r : 0;
      int arow;
      if constexpr (EXPERT) arow = rowtok[rowbase + rr]; else arow = rowbase + rr;
      gp[j] = A + (size_t)arow * KD + cg * 8;
      lp[j] = As + (w * 64 + j * 8) * BK;
    }
  } else if (w == 2) {              // B1 rows 0..63
    #pragma unroll
    for (int j = 0; j < 8; j++) {
      int r = j * 8 + lr;
      gp[j] = B1g + bmat + (size_t)(n * BN1 + r) * KD + cg * 8;
      lp[j] = Bs1 + (j * 8) * BK;
    }
  } else {                          // B2 rows 0..63
    #pragma unroll
    for (int j = 0; j < 8; j++) {
      int r = j * 8 + lr;
      gp[j] = B2g + bmat + (size_t)(n * BN1 + r) * KD + cg * 8;
      lp[j] = Bs2 + (j * 8) * BK;
    }
  }
  const int wm = w >> 1, wn = w & 1, q = l >> 4, rl = l & 15;
  const int r7 = rl & 7;
  f32x4 aG[4][2] = {}, aU[4][2] = {};

  for (int k0 = 0; k0 < KD; k0 += BK) {
    __syncthreads();
    #pragma unroll
    for (int j = 0; j < 8; j++) ld16(lp[j], gp[j] + k0);
    __syncthreads();
    #pragma unroll
    for (int kk = 0; kk < 2; kk++) {
      bf16x8 af[4], bf1[2], bf2[2];
      #pragma unroll
      for (int i = 0; i < 4; i++)
        af[i] = *(const bf16x8*)(As + (wm * 64 + i * 16 + rl) * BK + ((kk * 4 + q) ^ r7) * 8);
      #pragma unroll
      for (int i = 0; i < 2; i++) {
        bf1[i] = *(const bf16x8*)(Bs1 + (wn * 32 + i * 16 + rl) * BK + ((kk * 4 + q) ^ r7) * 8);
        bf2[i] = *(const bf16x8*)(Bs2 + (wn * 32 + i * 16 + rl) * BK + ((kk * 4 + q) ^ r7) * 8);
      }
      #pragma unroll
      for (int a = 0; a < 4; a++)
        #pragma unroll
        for (int b = 0; b < 2; b++) {
          aG[a][b] = __builtin_amdgcn_mfma_f32_16x16x32_bf16(af[a], bf1[b], aG[a][b], 0, 0, 0);
          aU[a][b] = __builtin_amdgcn_mfma_f32_16x16x32_bf16(af[a], bf2[b], aU[a][b], 0, 0, 0);
        }
    }
  }
  #pragma unroll
  for (int a = 0; a < 4; a++) {
    #pragma unroll
    for (int r = 0; r < 4; r++) {
      int row = wm * 64 + a * 16 + q * 4 + r;
      if (row < mval) {
        size_t ro = (size_t)(rowbase + row) * NOUT;
        #pragma unroll
        for (int b = 0; b < 2; b++) {
          int c = n * BN1 + wn * 32 + b * 16 + rl;
          float g = aG[a][b][r], u = aU[a][b][r];
          Ho[ro + c] = f2bf(g / (1.f + __expf(-g)) * u);
        }
      }
    }
  }
}

// GEMM2: 128x128 tile, optional split-K, atomic-add epilogue (out pre-zeroed).
template <int KD, int KSPLIT, bool EXPERT>
__global__ __launch_bounds__(256, 3)
void k_gemm2(const u16* __restrict__ A, const u16* __restrict__ Bg, float* __restrict__ out,
             const int* __restrict__ offs, const int* __restrict__ counts,
             const int* __restrict__ rowtok, const float* __restrict__ roww) {
  constexpr int MT = EXPERT ? MAXT : (Tt / BM);
  constexpr int KC = KD / KSPLIT;
  int bid = blockIdx.x;
  int n = bid & 7;                  // one N-tile per XCD (Hd/BN == 8)
  int idx = bid >> 3;
  int mt = idx % MT, kz = idx / MT;
  int rowbase, mval, eb = 0;
  if constexpr (EXPERT) {
    if (!tile_map(offs, counts, mt, rowbase, mval, eb)) return;
  } else {
    rowbase = mt * BM; mval = BM;
  }
  __shared__ u16 As[BM * BK], Bs[BN * BK];
  const int tid = threadIdx.x, w = tid >> 6, l = tid & 63;
  const int lr = l >> 3, cg = (l & 7) ^ lr;
  size_t bmat = EXPERT ? (size_t)eb * Hd * KD : 0;

  const u16* gp[8];
  u16* lp[8];
  if (w < 2) {                      // A rows w*64 .. w*64+63
    #pragma unroll
    for (int j = 0; j < 8; j++) {
      int r = w * 64 + j * 8 + lr;
      int rr = (r < mval) ? r : 0;
      gp[j] = A + (size_t)(rowbase + rr) * KD + cg * 8;
      lp[j] = As + (w * 64 + j * 8) * BK;
    }
  } else {                          // B rows (w-2)*64 .. +63
    #pragma unroll
    for (int j = 0; j < 8; j++) {
      int r = (w - 2) * 64 + j * 8 + lr;
      gp[j] = Bg + bmat + (size_t)(n * BN + r) * KD + cg * 8;
      lp[j] = Bs + ((w - 2) * 64 + j * 8) * BK;
    }
  }
  const int wm = w >> 1, wn = w & 1, q = l >> 4, rl = l & 15;
  const int r7 = rl & 7;
  f32x4 acc[4][4] = {};

  const int kend = kz * KC + KC;
  for (int k0 = kz * KC; k0 < kend; k0 += BK) {
    __syncthreads();
    #pragma unroll
    for (int j = 0; j < 8; j++) ld16(lp[j], gp[j] + k0);
    __syncthreads();
    #pragma unroll
    for (int kk = 0; kk < 2; kk++) {
      bf16x8 af[4], bf[4];
      #pragma unroll
      for (int i = 0; i < 4; i++) {
        af[i] = *(const bf16x8*)(As + (wm * 64 + i * 16 + rl) * BK + ((kk * 4 + q) ^ r7) * 8);
        bf[i] = *(const bf16x8*)(Bs + (wn * 64 + i * 16 + rl) * BK + ((kk * 4 + q) ^ r7) * 8);
      }
      #pragma unroll
      for (int a = 0; a < 4; a++)
        #pragma unroll
        for (int b = 0; b < 4; b++)
          acc[a][b] = __builtin_amdgcn_mfma_f32_16x16x32_bf16(af[a], bf[b], acc[a][b], 0, 0, 0);
    }
  }
  #pragma unroll
  for (int a = 0; a < 4; a++) {
    #pragma unroll
    for (int r = 0; r < 4; r++) {
      int row = wm * 64 + a * 16 + q * 4 + r;
      if (row < mval) {
        int grow = rowbase + row;
        float wt = 1.f;
        size_t o;
        if constexpr (EXPERT) {
          o = (size_t)rowtok[grow] * Hd;
          wt = roww[grow];
        } else {
          o = (size_t)grow * Hd;
        }
        #pragma unroll
        for (int b = 0; b < 4; b++) {
          int c = n * BN + wn * 64 + b * 16 + rl;
          atomicAdd(&out[o + c], wt * acc[a][b][r]);
        }
      }
    }
  }
}

// ---------------- launch ----------------

extern "C" void kernel_launch(void* const* d_in, const int* in_sizes, int n_in,
                              void* d_out, int out_size, void* d_ws, size_t ws_size,
                              hipStream_t stream) {
  const float* x   = (const float*)d_in[0];
  const float* rwm = (const float*)d_in[1];
  const float* Wg  = (const float*)d_in[2];
  const float* Wu  = (const float*)d_in[3];
  const float* Wd  = (const float*)d_in[4];
  const float* Sg  = (const float*)d_in[5];
  const float* Su  = (const float*)d_in[6];
  const float* Sd  = (const float*)d_in[7];
  float* out = (float*)d_out;

  uint8_t* p = (uint8_t*)d_ws;
  auto take = [&](size_t bytes) { uint8_t* r = p; p += ((bytes + 255) & ~(size_t)255); return r; };
  u16* xb   = (u16*)take((size_t)Tt * Hd * 2);
  u16* Wgt  = (u16*)take((size_t)NE * Id * Hd * 2);   // [E][I][H]
  u16* Wut  = (u16*)take((size_t)NE * Id * Hd * 2);
  u16* Wdt  = (u16*)take((size_t)NE * Hd * Id * 2);   // [E][H][I]
  u16* Sgt  = (u16*)take((size_t)ISd * Hd * 2);       // [IS][H]
  u16* Sut  = (u16*)take((size_t)ISd * Hd * 2);
  u16* Sdt  = (u16*)take((size_t)Hd * ISd * 2);       // [H][IS]
  u16* hbuf = (u16*)take((size_t)NR * Id * 2);        // reused: hs then h
  int*   sel    = (int*)take(Tt * 2 * 4);
  float* wts    = (float*)take(Tt * 2 * 4);
  int*   rowtok = (int*)take(NR * 4);
  float* roww   = (float*)take(NR * 4);
  int*   counts = (int*)take(NE * 4);
  int*   offs   = (int*)take(NE * 4);
  int*   cur    = (int*)take(NE * 4);

  hipMemsetAsync(counts, 0, NE * 4, stream);
  hipMemsetAsync(cur, 0, NE * 4, stream);
  hipMemsetAsync(out, 0, (size_t)out_size * 4, stream);  // gemm2s accumulate atomically

  k_cvt<<<(Tt * Hd / 8 + 255) / 256, 256, 0, stream>>>(x, xb, Tt * Hd);
  // Wg+Wu in one dispatch (z: 8 Wg then 8 Wu); Sg+Su likewise; Wd / Sd alone.
  k_tcvt<<<dim3(Id / 64, Hd / 64, 16), 256, 0, stream>>>(Wg, Wgt, Wu, Wut, Hd, Id, NE);
  k_tcvt<<<dim3(Hd / 64, Id / 64, NE), 256, 0, stream>>>(Wd, Wdt, Wd, Wdt, Id, Hd, NE);
  k_tcvt<<<dim3(ISd / 64, Hd / 64, 2), 256, 0, stream>>>(Sg, Sgt, Su, Sut, Hd, ISd, 1);
  k_tcvt<<<dim3(Hd / 64, ISd / 64, 1), 256, 0, stream>>>(Sd, Sdt, Sd, Sdt, ISd, Hd, 1);

  k_router<<<Tt, 256, 0, stream>>>(x, rwm, sel, wts, counts);
  k_offs<<<1, 1, 0, stream>>>(counts, offs);
  k_assign<<<Tt / 256, 256, 0, stream>>>(sel, wts, offs, cur, rowtok, roww);

  // shared expert
  k_gemm1<ISd, false><<<(Tt / BM) * (ISd / BN1), 256, 0, stream>>>(
      xb, Sgt, Sut, hbuf, nullptr, nullptr, nullptr);
  k_gemm2<ISd, 2, false><<<8 * (Tt / BM) * 2, 256, 0, stream>>>(
      hbuf, Sdt, out, nullptr, nullptr, nullptr, nullptr);
  // routed experts
  k_gemm1<Id, true><<<MAXT * (Id / BN1), 256, 0, stream>>>(
      xb, Wgt, Wut, hbuf, offs, counts, rowtok);
  k_gemm2<Id, 1, true><<<8 * MAXT, 256, 0, stream>>>(
      hbuf, Wdt, out, offs, counts, rowtok, roww);
}

// Round 4
// 605.965 us; speedup vs baseline: 1.3096x; 1.1782x over previous
//
#include <hip/hip_runtime.h>
#include <hip/hip_bf16.h>
#include <stdint.h>

// MoE: T=4096 tokens, H=1024, E=8 (top-2), I=2048, IS=4096. fp32 in/out.
// bf16 MFMA pipeline: one merged transpose dispatch, LDS-staged router,
// merged (shared+expert) BK=64 GEMMs with global_load_lds + XOR bank swizzle.

typedef __attribute__((ext_vector_type(8))) short bf16x8;   // MFMA A/B frag
typedef __attribute__((ext_vector_type(4))) float f32x4;    // MFMA C/D frag
typedef unsigned short u16;

static constexpr int Tt  = 4096;
static constexpr int Hd  = 1024;
static constexpr int NE  = 8;
static constexpr int Id  = 2048;
static constexpr int ISd = 4096;
static constexpr int NR  = Tt * 2;
static constexpr int BM = 128, BN = 128, BN1 = 64, BK = 64;
static constexpr int MAXT = NR / BM + NE;          // 72 worst-case expert M-tiles
static constexpr int G1_SH = (Tt / BM) * (ISd / BN1);   // 2048 shared gemm1 blocks
static constexpr int G1_EX = MAXT * (Id / BN1);         // 2304 expert gemm1 blocks
static constexpr int G2_SH = 8 * (Tt / BM) * 2;         // 512 shared gemm2 (ksplit 2)
static constexpr int G2_EX = 8 * MAXT;                  // 576 expert gemm2

__device__ __forceinline__ u16 f2bf(float f) {  // RNE float->bf16
  union { float f; uint32_t u; } v; v.f = f;
  uint32_t u = v.u;
  u += 0x7fffu + ((u >> 16) & 1u);
  return (u16)(u >> 16);
}

__device__ __forceinline__ void ld16(void* l, const void* g) {
  __builtin_amdgcn_global_load_lds((const __attribute__((address_space(1))) void*)g,
                                   (__attribute__((address_space(3))) void*)l, 16, 0, 0);
}

// ---------------- preprocessing ----------------

__global__ void k_cvt(const float* __restrict__ s, u16* __restrict__ d, int n) {
  int i = (blockIdx.x * 256 + threadIdx.x) * 8;
  if (i >= n) return;
  float4 a = *(const float4*)(s + i);
  float4 b = *(const float4*)(s + i + 4);
  union { u16 h[8]; uint4 v; } o;
  o.h[0] = f2bf(a.x); o.h[1] = f2bf(a.y); o.h[2] = f2bf(a.z); o.h[3] = f2bf(a.w);
  o.h[4] = f2bf(b.x); o.h[5] = f2bf(b.y); o.h[6] = f2bf(b.z); o.h[7] = f2bf(b.w);
  *(uint4*)(d + i) = o.v;
}

// ALL weight transposes in one dispatch. fp32 [z][K][N] -> bf16 [z][N][K], 64x64 tiles.
// Segments: Wg(8z), Wu(8z), Wd(8z), Sg, Su, Sd.
__global__ __launch_bounds__(256)
void k_tcvt(const float* __restrict__ s0, u16* __restrict__ d0,
            const float* __restrict__ s1, u16* __restrict__ d1,
            const float* __restrict__ s2, u16* __restrict__ d2,
            const float* __restrict__ s3, u16* __restrict__ d3,
            const float* __restrict__ s4, u16* __restrict__ d4,
            const float* __restrict__ s5, u16* __restrict__ d5) {
  // per-seg: start block, K, N   (blocks/z = (N/64)*(K/64))
  constexpr int ST[6] = {0, 4096, 8192, 12288, 13312, 14336};
  constexpr int KS[6] = {1024, 1024, 2048, 1024, 1024, 4096};
  constexpr int NS[6] = {2048, 2048, 1024, 4096, 4096, 1024};
  int bid = blockIdx.x;
  int seg = 0;
  #pragma unroll
  for (int i = 1; i < 6; i++) if (bid >= ST[i]) seg = i;
  const float* S; u16* D;
  switch (seg) {
    case 0: S = s0; D = d0; break;
    case 1: S = s1; D = d1; break;
    case 2: S = s2; D = d2; break;
    case 3: S = s3; D = d3; break;
    case 4: S = s4; D = d4; break;
    default: S = s5; D = d5; break;
  }
  int K = KS[seg], N = NS[seg];
  int lb = bid - ST[seg];
  int perz = (N >> 6) * (K >> 6);
  int z = lb / perz, r = lb - z * perz;
  int bx = r % (N >> 6), by = r / (N >> 6);
  S += (size_t)z * K * N; D += (size_t)z * K * N;
  int n0 = bx * 64, k0 = by * 64;

  __shared__ float sm[64][65];
  int tid = threadIdx.x;
  int rr = tid >> 4, cc = (tid & 15) * 4;
  #pragma unroll
  for (int i = 0; i < 4; i++) {
    float4 v = *(const float4*)&S[(size_t)(k0 + i * 16 + rr) * N + n0 + cc];
    sm[i * 16 + rr][cc] = v.x; sm[i * 16 + rr][cc + 1] = v.y;
    sm[i * 16 + rr][cc + 2] = v.z; sm[i * 16 + rr][cc + 3] = v.w;
  }
  __syncthreads();
  int nn = tid >> 3, kc = (tid & 7) * 8;
  #pragma unroll
  for (int i = 0; i < 2; i++) {
    int n = i * 32 + nn;
    union { u16 h[8]; uint4 v; } o;
    #pragma unroll
    for (int t = 0; t < 8; t++) o.h[t] = f2bf(sm[kc + t][n]);
    *(uint4*)&D[(size_t)(n0 + n) * K + k0 + kc] = o.v;
  }
}

// ---------------- router ----------------
// 256 blocks x 256 thr. rwm (32 KB) in LDS. 16 thr/token, interleaved float4
// chunks (lanes 0-15 cover 256 B contiguous: coalesced + conflict-free).

__global__ __launch_bounds__(256)
void k_router(const float* __restrict__ x, const float* __restrict__ rwm,
              int* __restrict__ sel, float* __restrict__ wts,
              int* __restrict__ counts) {
  __shared__ float w[NE * Hd];
  __shared__ int lcnt[NE];
  int tid = threadIdx.x;
  if (tid < NE) lcnt[tid] = 0;
  #pragma unroll
  for (int i = 0; i < 8; i++) {
    int idx = (i * 256 + tid) * 4;
    *(float4*)&w[idx] = *(const float4*)&rwm[idx];
  }
  __syncthreads();
  int tok = blockIdx.x * 16 + (tid >> 4);
  int part = tid & 15;
  const float* xt = x + (size_t)tok * Hd;
  float p[NE] = {};
  #pragma unroll
  for (int j = 0; j < 16; j++) {
    int off = j * 64 + part * 4;
    float4 v = *(const float4*)&xt[off];
    #pragma unroll
    for (int e = 0; e < NE; e++) {
      float4 wv = *(const float4*)&w[e * Hd + off];
      p[e] += v.x * wv.x + v.y * wv.y + v.z * wv.z + v.w * wv.w;
    }
  }
  #pragma unroll
  for (int e = 0; e < NE; e++)
    #pragma unroll
    for (int o = 1; o < 16; o <<= 1)
      p[e] += __shfl_xor(p[e], o, 64);
  if (part == 0) {
    int e0 = 0;
    for (int e = 1; e < NE; e++) if (p[e] > p[e0]) e0 = e;   // first-occurrence argmax
    int e1 = -1;
    for (int e = 0; e < NE; e++) { if (e == e0) continue; if (e1 < 0 || p[e] > p[e1]) e1 = e; }
    float w0 = 1.f / (1.f + expf(p[e1] - p[e0]));            // softmax over top-2
    sel[tok * 2] = e0; sel[tok * 2 + 1] = e1;
    wts[tok * 2] = w0; wts[tok * 2 + 1] = 1.f - w0;
    atomicAdd(&lcnt[e0], 1); atomicAdd(&lcnt[e1], 1);
  }
  __syncthreads();
  if (tid < NE) atomicAdd(&counts[tid], lcnt[tid]);
}

__global__ void k_assign(const int* __restrict__ sel, const float* __restrict__ wts,
                         const int* __restrict__ counts, int* __restrict__ cur,
                         int* __restrict__ rowtok, float* __restrict__ roww) {
  int t = blockIdx.x * 256 + threadIdx.x;
  if (t >= Tt) return;
  int offs[NE];
  int a = 0;
  #pragma unroll
  for (int e = 0; e < NE; e++) { offs[e] = a; a += counts[e]; }
  #pragma unroll
  for (int k = 0; k < 2; k++) {
    int e = sel[t * 2 + k];
    int r = offs[e] + atomicAdd(&cur[e], 1);
    rowtok[r] = t; roww[r] = wts[t * 2 + k];
  }
}

// ---------------- GEMM helpers ----------------

// slot -> (rowbase, mval, expert); offsets derived from counts prefix-sum.
__device__ __forceinline__ bool tile_map(const int* counts, int slot,
                                         int& rowbase, int& mval, int& e_out) {
  int acc = 0, base = 0, e = -1;
  for (int i = 0; i < NE; i++) {
    int c = counts[i];
    int nt = (c + BM - 1) / BM;
    if (e < 0 && slot < acc + nt) {
      int tl = slot - acc;
      e = i;
      rowbase = base + tl * BM;
      int rem = c - tl * BM;
      mval = rem < BM ? rem : BM;
    }
    acc += nt; base += c;
  }
  e_out = e;
  return e >= 0;
}

// LDS layout (BK=64): row = 128 B = 8 chunks of 16 B; chunk c of row r at slot
// c ^ (r&7). Staging lane l in an 8-row unit: row l>>3, slot l&7 -> fetches
// logical chunk (l&7)^(l>>3). Frag reads mirror -> 2-way max (free).

// Merged GEMM1 (shared + expert): 128x64 tile, dual B, fused SwiGLU -> bf16.
__global__ __launch_bounds__(256, 3)
void k_gemm1(const u16* __restrict__ A,
             const u16* __restrict__ Sgt, const u16* __restrict__ Sut, u16* __restrict__ hs,
             const u16* __restrict__ Wgt, const u16* __restrict__ Wut, u16* __restrict__ h,
             const int* __restrict__ counts, const int* __restrict__ rowtok) {
  constexpr int KD = Hd;
  int bid = blockIdx.x;
  bool gather;
  const u16 *B1g, *B2g; u16* Ho;
  int NOUT, n, mt, rowbase, mval, eb = 0;
  if (bid < G1_SH) {
    gather = false; NOUT = ISd; B1g = Sgt; B2g = Sut; Ho = hs;
    int xcd = bid & 7, idx = bid >> 3;     // slabN = (ISd/BN1)/8 = 8
    n = xcd * 8 + (idx & 7); mt = idx >> 3;
    rowbase = mt * BM; mval = BM;
  } else {
    gather = true; NOUT = Id; Ho = h;
    int b2 = bid - G1_SH;
    int xcd = b2 & 7, idx = b2 >> 3;       // slabN = (Id/BN1)/8 = 4
    n = xcd * 4 + (idx & 3); mt = idx >> 2;
    if (!tile_map(counts, mt, rowbase, mval, eb)) return;
    size_t bmat = (size_t)eb * Id * KD;
    B1g = Wgt + bmat; B2g = Wut + bmat;
  }
  __shared__ u16 As[BM * BK], Bs1[BN1 * BK], Bs2[BN1 * BK];
  const int tid = threadIdx.x, w = tid >> 6, l = tid & 63;
  const int lr = l >> 3, cg = (l & 7) ^ lr;

  const u16* gp[8];
  u16* lp[8];
  if (w < 2) {                      // A rows w*64 .. +63
    #pragma unroll
    for (int j = 0; j < 8; j++) {
      int r = w * 64 + j * 8 + lr;
      int rr = (r < mval) ? r : 0;
      int arow = gather ? rowtok[rowbase + rr] : (rowbase + rr);
      gp[j] = A + (size_t)arow * KD + cg * 8;
      lp[j] = As + (w * 64 + j * 8) * BK;
    }
  } else if (w == 2) {              // B1 rows 0..63
    #pragma unroll
    for (int j = 0; j < 8; j++) {
      int r = j * 8 + lr;
      gp[j] = B1g + (size_t)(n * BN1 + r) * KD + cg * 8;
      lp[j] = Bs1 + (j * 8) * BK;
    }
  } else {                          // B2 rows 0..63
    #pragma unroll
    for (int j = 0; j < 8; j++) {
      int r = j * 8 + lr;
      gp[j] = B2g + (size_t)(n * BN1 + r) * KD + cg * 8;
      lp[j] = Bs2 + (j * 8) * BK;
    }
  }
  const int wm = w >> 1, wn = w & 1, q = l >> 4, rl = l & 15;
  const int r7 = rl & 7;
  f32x4 aG[4][2] = {}, aU[4][2] = {};

  for (int k0 = 0; k0 < KD; k0 += BK) {
    __syncthreads();
    #pragma unroll
    for (int j = 0; j < 8; j++) ld16(lp[j], gp[j] + k0);
    __syncthreads();
    #pragma unroll
    for (int kk = 0; kk < 2; kk++) {
      bf16x8 af[4], bf1[2], bf2[2];
      #pragma unroll
      for (int i = 0; i < 4; i++)
        af[i] = *(const bf16x8*)(As + (wm * 64 + i * 16 + rl) * BK + ((kk * 4 + q) ^ r7) * 8);
      #pragma unroll
      for (int i = 0; i < 2; i++) {
        bf1[i] = *(const bf16x8*)(Bs1 + (wn * 32 + i * 16 + rl) * BK + ((kk * 4 + q) ^ r7) * 8);
        bf2[i] = *(const bf16x8*)(Bs2 + (wn * 32 + i * 16 + rl) * BK + ((kk * 4 + q) ^ r7) * 8);
      }
      #pragma unroll
      for (int a = 0; a < 4; a++)
        #pragma unroll
        for (int b = 0; b < 2; b++) {
          aG[a][b] = __builtin_amdgcn_mfma_f32_16x16x32_bf16(af[a], bf1[b], aG[a][b], 0, 0, 0);
          aU[a][b] = __builtin_amdgcn_mfma_f32_16x16x32_bf16(af[a], bf2[b], aU[a][b], 0, 0, 0);
        }
    }
  }
  #pragma unroll
  for (int a = 0; a < 4; a++) {
    #pragma unroll
    for (int r = 0; r < 4; r++) {
      int row = wm * 64 + a * 16 + q * 4 + r;
      if (row < mval) {
        size_t ro = (size_t)(rowbase + row) * NOUT;
        #pragma unroll
        for (int b = 0; b < 2; b++) {
          int c = n * BN1 + wn * 32 + b * 16 + rl;
          float g = aG[a][b][r], u = aU[a][b][r];
          Ho[ro + c] = f2bf(g / (1.f + __expf(-g)) * u);
        }
      }
    }
  }
}

// Merged GEMM2 (shared ksplit-2 + expert): 128x128, atomic-add into zeroed out.
__global__ __launch_bounds__(256, 3)
void k_gemm2(const u16* __restrict__ hs, const u16* __restrict__ Sdt,
             const u16* __restrict__ h, const u16* __restrict__ Wdt,
             float* __restrict__ out,
             const int* __restrict__ counts, const int* __restrict__ rowtok,
             const float* __restrict__ roww) {
  int bid = blockIdx.x;
  bool gather;
  const u16 *A, *Bg;
  int n, rowbase, mval, eb = 0, kstart, KDrow;
  if (bid < G2_SH) {
    gather = false; KDrow = ISd;
    n = bid & 7;
    int idx = bid >> 3;
    int mt = idx & 31, kz = idx >> 5;      // MT=32, ksplit 2
    rowbase = mt * BM; mval = BM;
    kstart = kz * (ISd / 2);
    A = hs; Bg = Sdt;
  } else {
    gather = true; KDrow = Id;
    int b2 = bid - G2_SH;
    n = b2 & 7;
    int mt = b2 >> 3;
    if (!tile_map(counts, mt, rowbase, mval, eb)) return;
    kstart = 0;
    A = h; Bg = Wdt + (size_t)eb * Hd * Id;
  }
  __shared__ u16 As[BM * BK], Bs[BN * BK];
  const int tid = threadIdx.x, w = tid >> 6, l = tid & 63;
  const int lr = l >> 3, cg = (l & 7) ^ lr;

  const u16* gp[8];
  u16* lp[8];
  if (w < 2) {                      // A rows w*64 .. +63
    #pragma unroll
    for (int j = 0; j < 8; j++) {
      int r = w * 64 + j * 8 + lr;
      int rr = (r < mval) ? r : 0;
      gp[j] = A + (size_t)(rowbase + rr) * KDrow + cg * 8;
      lp[j] = As + (w * 64 + j * 8) * BK;
    }
  } else {                          // B rows (w-2)*64 .. +63
    #pragma unroll
    for (int j = 0; j < 8; j++) {
      int r = (w - 2) * 64 + j * 8 + lr;
      gp[j] = Bg + (size_t)(n * BN + r) * KDrow + cg * 8;
      lp[j] = Bs + ((w - 2) * 64 + j * 8) * BK;
    }
  }
  const int wm = w >> 1, wn = w & 1, q = l >> 4, rl = l & 15;
  const int r7 = rl & 7;
  f32x4 acc[4][4] = {};

  const int kend = kstart + 2048;   // shared: ISd/2; expert: Id — both 2048
  for (int k0 = kstart; k0 < kend; k0 += BK) {
    __syncthreads();
    #pragma unroll
    for (int j = 0; j < 8; j++) ld16(lp[j], gp[j] + k0);
    __syncthreads();
    #pragma unroll
    for (int kk = 0; kk < 2; kk++) {
      bf16x8 af[4], bf[4];
      #pragma unroll
      for (int i = 0; i < 4; i++) {
        af[i] = *(const bf16x8*)(As + (wm * 64 + i * 16 + rl) * BK + ((kk * 4 + q) ^ r7) * 8);
        bf[i] = *(const bf16x8*)(Bs + (wn * 64 + i * 16 + rl) * BK + ((kk * 4 + q) ^ r7) * 8);
      }
      #pragma unroll
      for (int a = 0; a < 4; a++)
        #pragma unroll
        for (int b = 0; b < 4; b++)
          acc[a][b] = __builtin_amdgcn_mfma_f32_16x16x32_bf16(af[a], bf[b], acc[a][b], 0, 0, 0);
    }
  }
  #pragma unroll
  for (int a = 0; a < 4; a++) {
    #pragma unroll
    for (int r = 0; r < 4; r++) {
      int row = wm * 64 + a * 16 + q * 4 + r;
      if (row < mval) {
        int grow = rowbase + row;
        float wt = 1.f;
        size_t o;
        if (gather) { o = (size_t)rowtok[grow] * Hd; wt = roww[grow]; }
        else o = (size_t)grow * Hd;
        #pragma unroll
        for (int b = 0; b < 4; b++) {
          int c = n * BN + wn * 64 + b * 16 + rl;
          atomicAdd(&out[o + c], wt * acc[a][b][r]);
        }
      }
    }
  }
}

// ---------------- launch ----------------

extern "C" void kernel_launch(void* const* d_in, const int* in_sizes, int n_in,
                              void* d_out, int out_size, void* d_ws, size_t ws_size,
                              hipStream_t stream) {
  const float* x   = (const float*)d_in[0];
  const float* rwm = (const float*)d_in[1];
  const float* Wg  = (const float*)d_in[2];
  const float* Wu  = (const float*)d_in[3];
  const float* Wd  = (const float*)d_in[4];
  const float* Sg  = (const float*)d_in[5];
  const float* Su  = (const float*)d_in[6];
  const float* Sd  = (const float*)d_in[7];
  float* out = (float*)d_out;

  uint8_t* p = (uint8_t*)d_ws;
  auto take = [&](size_t bytes) { uint8_t* r = p; p += ((bytes + 255) & ~(size_t)255); return r; };
  u16* xb   = (u16*)take((size_t)Tt * Hd * 2);
  u16* Wgt  = (u16*)take((size_t)NE * Id * Hd * 2);   // [E][I][H]
  u16* Wut  = (u16*)take((size_t)NE * Id * Hd * 2);
  u16* Wdt  = (u16*)take((size_t)NE * Hd * Id * 2);   // [E][H][I]
  u16* Sgt  = (u16*)take((size_t)ISd * Hd * 2);       // [IS][H]
  u16* Sut  = (u16*)take((size_t)ISd * Hd * 2);
  u16* Sdt  = (u16*)take((size_t)Hd * ISd * 2);       // [H][IS]
  u16* hs   = (u16*)take((size_t)Tt * ISd * 2);       // shared intermediate
  u16* h    = (u16*)take((size_t)NR * Id * 2);        // expert intermediate
  int*   sel    = (int*)take(Tt * 2 * 4);
  float* wts    = (float*)take(Tt * 2 * 4);
  int*   rowtok = (int*)take(NR * 4);
  float* roww   = (float*)take(NR * 4);
  int*   ctrl   = (int*)take(2 * NE * 4);             // counts | cur
  int* counts = ctrl, *cur = ctrl + NE;

  hipMemsetAsync(ctrl, 0, 2 * NE * 4, stream);
  hipMemsetAsync(out, 0, (size_t)out_size * 4, stream);  // gemm2 accumulates atomically

  k_cvt<<<(Tt * Hd / 8 + 255) / 256, 256, 0, stream>>>(x, xb, Tt * Hd);
  k_tcvt<<<15360, 256, 0, stream>>>(Wg, Wgt, Wu, Wut, Wd, Wdt, Sg, Sgt, Su, Sut, Sd, Sdt);
  k_router<<<Tt / 16, 256, 0, stream>>>(x, rwm, sel, wts, counts);
  k_assign<<<Tt / 256, 256, 0, stream>>>(sel, wts, counts, cur, rowtok, roww);

  k_gemm1<<<G1_SH + G1_EX, 256, 0, stream>>>(xb, Sgt, Sut, hs, Wgt, Wut, h, counts, rowtok);
  k_gemm2<<<G2_SH + G2_EX, 256, 0, stream>>>(hs, Sdt, h, Wdt, out, counts, rowtok, roww);
}